// Round 7
// baseline (86.305 us; speedup 1.0000x reference)
//
#include <hip/hip_runtime.h>

#define WAVE 64
#define CHUNK 8

__global__ __launch_bounds__(256) void hs_main(
    const float* __restrict__ emb,        // [N, 256]
    const float* __restrict__ fc,         // [V-1, 256]
    const int*   __restrict__ target,     // [N]
    const int*   __restrict__ path_idx,   // [V, L]
    const float* __restrict__ path_codes, // [V, L]
    const float* __restrict__ path_mask,  // [V, L]
    unsigned int* __restrict__ count,     // zeroed via memsetAsync each call
    float2* __restrict__ partials,        // [gridDim.x]
    float*  __restrict__ out,
    int N, int L, int nblocks)
{
    const int lane   = threadIdx.x & (WAVE - 1);
    const int wid    = threadIdx.x >> 6;
    const int gwave  = blockIdx.x * (blockDim.x >> 6) + wid;
    const int nwaves = nblocks * (blockDim.x >> 6);

    float bce_acc = 0.0f;   // identical on all lanes of a wave
    float cnt_acc = 0.0f;

    for (int row = gwave; row < N; row += nwaves) {
        const float4 e = *reinterpret_cast<const float4*>(emb + (size_t)row * 256 + lane * 4);
        const int t = target[row];

        // path metadata: lane l holds entry l (coalesced); padded entries are 0
        int   my_pi = 0;
        float my_pc = 0.0f;
        float my_pm = 0.0f;
        if (lane < L) {
            const size_t off = (size_t)t * L + lane;
            my_pi = path_idx[off];
            my_pc = path_codes[off];
            my_pm = path_mask[off];
        }
        const unsigned long long bal = __ballot(my_pm != 0.0f);
        const int plen = __popcll(bal);       // mask is a prefix, plen <= 64
        cnt_acc += (float)plen;

        for (int base = 0; base < plen; base += CHUNK) {
            // --- broadcast 8 node ids ---
            int node[CHUNK];
            #pragma unroll
            for (int k = 0; k < CHUNK; ++k)
                node[k] = __shfl(my_pi, base + k, WAVE);   // pad -> 0 (safe row)

            // --- 8 unconditional gathers, grouped => real MLP=8 ---
            float4 w[CHUNK];
            #pragma unroll
            for (int k = 0; k < CHUNK; ++k)
                w[k] = *reinterpret_cast<const float4*>(fc + (size_t)node[k] * 256 + lane * 4);

            // --- codes broadcast overlaps gather latency ---
            float y[CHUNK];
            #pragma unroll
            for (int k = 0; k < CHUNK; ++k)
                y[k] = __shfl(my_pc, base + k, WAVE);

            // --- dots ---
            float part[CHUNK];
            #pragma unroll
            for (int k = 0; k < CHUNK; ++k)
                part[k] = e.x * w[k].x + e.y * w[k].y + e.z * w[k].z + e.w * w[k].w;

            // --- 8 independent butterflies, stages interleave ---
            #pragma unroll
            for (int off = 32; off > 0; off >>= 1) {
                #pragma unroll
                for (int k = 0; k < CHUNK; ++k)
                    part[k] += __shfl_xor(part[k], off, WAVE);
            }

            // --- BCE on all lanes, arithmetic mask (no loads) ---
            #pragma unroll
            for (int k = 0; k < CHUNK; ++k) {
                const float m = (base + k < plen) ? 1.0f : 0.0f;
                const float p = part[k];
                const float bce = fmaxf(p, 0.0f) - p * y[k]
                                + __logf(1.0f + __expf(-fabsf(p)));
                bce_acc += m * bce;
            }
        }
    }

    // block reduction -> one float2 per block (bce_acc identical per wave lane)
    __shared__ float s_b[4], s_c[4];
    __shared__ int s_last;
    if (lane == 0) { s_b[wid] = bce_acc; s_c[wid] = cnt_acc; }
    __syncthreads();
    if (threadIdx.x == 0) {
        const int nw = blockDim.x >> 6;
        float b = 0.0f, c = 0.0f;
        for (int i = 0; i < nw; ++i) { b += s_b[i]; c += s_c[i]; }
        partials[blockIdx.x] = make_float2(b, c);
        __threadfence();
        const unsigned int old = atomicAdd(count, 1u);
        s_last = (old == (unsigned int)(nblocks - 1)) ? 1 : 0;
    }
    __syncthreads();

    // last arriving block reduces all partials and writes the scalar
    if (s_last) {
        __threadfence();
        const volatile float* vp = (const volatile float*)partials;
        double b = 0.0, c = 0.0;
        for (int i = threadIdx.x; i < nblocks; i += blockDim.x) {
            b += (double)vp[2 * i];
            c += (double)vp[2 * i + 1];
        }
        __shared__ double db[256], dc[256];
        db[threadIdx.x] = b; dc[threadIdx.x] = c;
        __syncthreads();
        for (int s = 128; s > 0; s >>= 1) {
            if (threadIdx.x < (unsigned)s) {
                db[threadIdx.x] += db[threadIdx.x + s];
                dc[threadIdx.x] += dc[threadIdx.x + s];
            }
            __syncthreads();
        }
        if (threadIdx.x == 0) out[0] = (float)(db[0] / dc[0]);
    }
}

extern "C" void kernel_launch(void* const* d_in, const int* in_sizes, int n_in,
                              void* d_out, int out_size, void* d_ws, size_t ws_size,
                              hipStream_t stream) {
    const float* emb        = (const float*)d_in[0];
    const float* fc         = (const float*)d_in[1];
    const int*   target     = (const int*)d_in[2];
    const int*   path_idx   = (const int*)d_in[3];
    const float* path_codes = (const float*)d_in[4];
    const float* path_mask  = (const float*)d_in[5];

    const int N = in_sizes[2];
    const int V = in_sizes[1] / 256 + 1;
    const int L = in_sizes[3] / V;

    unsigned int* count    = (unsigned int*)d_ws;
    float2*       partials = (float2*)((char*)d_ws + 256);
    float*        out      = (float*)d_out;

    const int block = 256;                        // 4 waves/block, 1 wave per row
    int nblocks = (N * WAVE + block - 1) / block; // 2048 blocks
    if (nblocks < 1) nblocks = 1;

    hipMemsetAsync(count, 0, sizeof(unsigned int), stream);
    hs_main<<<nblocks, block, 0, stream>>>(emb, fc, target, path_idx, path_codes,
                                           path_mask, count, partials, out,
                                           N, L, nblocks);
}

// Round 8
// 24.122 us; speedup vs baseline: 3.5778x; 3.5778x over previous
//
#include <hip/hip_runtime.h>

#define LD4(p) (*reinterpret_cast<const float4*>(p))

__device__ __forceinline__ float dot16(float4 e0, float4 e1, float4 e2, float4 e3,
                                       float4 w0, float4 w1, float4 w2, float4 w3) {
    return e0.x*w0.x + e0.y*w0.y + e0.z*w0.z + e0.w*w0.w
         + e1.x*w1.x + e1.y*w1.y + e1.z*w1.z + e1.w*w1.w
         + e2.x*w2.x + e2.y*w2.y + e2.z*w2.z + e2.w*w2.w
         + e3.x*w3.x + e3.y*w3.y + e3.z*w3.z + e3.w*w3.w;
}

__device__ __forceinline__ float red16(float q) {
    q += __shfl_xor(q, 1, 16);
    q += __shfl_xor(q, 2, 16);
    q += __shfl_xor(q, 4, 16);
    q += __shfl_xor(q, 8, 16);
    return q;   // all 16 lanes of the group hold the group's sum
}

__device__ __forceinline__ float bce_term(float q, float y, float m) {
    return m * (fmaxf(q, 0.0f) - q * y + __logf(1.0f + __expf(-fabsf(q))));
}

// One 64-lane wave per row. The 4 16-lane groups process path entries
// {4j+0, 4j+1, 4j+2, 4j+3} in parallel: 4 visits per round, one bpermute /
// one 4-stage reduce / one BCE block per round instead of per visit.
__global__ __launch_bounds__(256) void hs_main(
    const float* __restrict__ emb,        // [N, 256]
    const float* __restrict__ fc,         // [V-1, 256]
    const int*   __restrict__ target,     // [N]
    const int*   __restrict__ path_idx,   // [V, L]
    const float* __restrict__ path_codes, // [V, L]
    const float* __restrict__ path_mask,  // [V, L]
    float2* __restrict__ partials,        // [gridDim.x]
    int N, int L)
{
    const int lane = threadIdx.x & 63;
    const int g    = lane >> 4;           // group 0..3
    const int li   = lane & 15;           // lane in group
    const int wid  = threadIdx.x >> 6;
    const int gwave  = blockIdx.x * (blockDim.x >> 6) + wid;
    const int nwaves = gridDim.x * (blockDim.x >> 6);

    float bce_acc = 0.0f;   // per-lane: its group's bce sum (copies within group)
    float cnt_acc = 0.0f;   // wave-uniform

    for (int row = gwave; row < N; row += nwaves) {
        // each group holds a full copy of the embedding row: lane li owns
        // floats [li*16, li*16+16)
        const float* erow = emb + (size_t)row * 256 + li * 16;
        const float4 e0 = LD4(erow), e1 = LD4(erow + 4),
                     e2 = LD4(erow + 8), e3 = LD4(erow + 12);
        const int t = target[row];

        // path metadata: lane l holds entry l (coalesced); padded entries 0
        int pi = 0; float pc = 0.0f, pm = 0.0f;
        if (lane < L) {
            const size_t off = (size_t)t * L + lane;
            pi = path_idx[off];
            pc = path_codes[off];
            pm = path_mask[off];
        }
        const unsigned long long bal = __ballot(pm != 0.0f);
        const int plen = __popcll(bal);   // mask is a prefix, plen <= 64
        cnt_acc += (float)plen;

        // two rounds (8 visits) per iteration: 8 independent float4 loads/lane
        for (int j4 = 0; j4 < plen; j4 += 8) {
            const int i0 = j4 + g;            // <= 63 always
            const int i1 = j4 + 4 + g;        // <= 63 always
            const int n0 = __shfl(pi, i0, 64);
            const int n1 = __shfl(pi, i1, 64);
            const float* p0 = fc + ((size_t)n0 << 8) + li * 16;
            const float* p1 = fc + ((size_t)n1 << 8) + li * 16;
            const float4 a0 = LD4(p0), a1 = LD4(p0 + 4),
                         a2 = LD4(p0 + 8), a3 = LD4(p0 + 12);
            const float4 b0 = LD4(p1), b1 = LD4(p1 + 4),
                         b2 = LD4(p1 + 8), b3 = LD4(p1 + 12);
            const float y0 = __shfl(pc, i0, 64);
            const float y1 = __shfl(pc, i1, 64);
            const float m0 = (i0 < plen) ? 1.0f : 0.0f;
            const float m1 = (i1 < plen) ? 1.0f : 0.0f;

            float q0 = dot16(e0, e1, e2, e3, a0, a1, a2, a3);
            float q1 = dot16(e0, e1, e2, e3, b0, b1, b2, b3);
            q0 = red16(q0);
            q1 = red16(q1);

            bce_acc += bce_term(q0, y0, m0);
            bce_acc += bce_term(q1, y1, m1);
        }
    }

    // sum the 4 groups' totals across the wave (each lane holds a group copy)
    bce_acc += __shfl_xor(bce_acc, 16, 64);
    bce_acc += __shfl_xor(bce_acc, 32, 64);
    // cnt_acc is wave-uniform: no reduction needed

    __shared__ float s_b[4], s_c[4];
    if (lane == 0) { s_b[wid] = bce_acc; s_c[wid] = cnt_acc; }
    __syncthreads();
    if (threadIdx.x == 0) {
        const int nw = blockDim.x >> 6;
        float b = 0.0f, c = 0.0f;
        for (int i = 0; i < nw; ++i) { b += s_b[i]; c += s_c[i]; }
        partials[blockIdx.x] = make_float2(b, c);
    }
}

__global__ __launch_bounds__(256) void hs_fin(
    const float2* __restrict__ partials, int nparts, float* __restrict__ out)
{
    double b = 0.0, c = 0.0;
    for (int i = threadIdx.x; i < nparts; i += blockDim.x) {
        const float2 p = partials[i];
        b += (double)p.x;
        c += (double)p.y;
    }
    __shared__ double sb[256], sc[256];
    sb[threadIdx.x] = b; sc[threadIdx.x] = c;
    __syncthreads();
    for (int s = 128; s > 0; s >>= 1) {
        if (threadIdx.x < s) {
            sb[threadIdx.x] += sb[threadIdx.x + s];
            sc[threadIdx.x] += sc[threadIdx.x + s];
        }
        __syncthreads();
    }
    if (threadIdx.x == 0) out[0] = (float)(sb[0] / sc[0]);
}

extern "C" void kernel_launch(void* const* d_in, const int* in_sizes, int n_in,
                              void* d_out, int out_size, void* d_ws, size_t ws_size,
                              hipStream_t stream) {
    const float* emb        = (const float*)d_in[0];
    const float* fc         = (const float*)d_in[1];
    const int*   target     = (const int*)d_in[2];
    const int*   path_idx   = (const int*)d_in[3];
    const float* path_codes = (const float*)d_in[4];
    const float* path_mask  = (const float*)d_in[5];

    const int N = in_sizes[2];
    const int V = in_sizes[1] / 256 + 1;
    const int L = in_sizes[3] / V;

    float2* partials = (float2*)d_ws;
    float*  out      = (float*)d_out;

    const int block = 256;                        // 4 waves/block, 1 row per wave
    int nblocks = (N + 3) / 4;                    // 2048 blocks -> 8192 waves
    if (nblocks < 1) nblocks = 1;
    if ((size_t)nblocks * sizeof(float2) > ws_size)
        nblocks = (int)(ws_size / sizeof(float2));

    hs_main<<<nblocks, block, 0, stream>>>(emb, fc, target, path_idx, path_codes,
                                           path_mask, partials, N, L);
    hs_fin<<<1, block, 0, stream>>>(partials, nblocks, out);
}